// Round 4
// baseline (299.854 us; speedup 1.0000x reference)
//
#include <hip/hip_runtime.h>
#include <hip/hip_cooperative_groups.h>
#include <math.h>

namespace cg = cooperative_groups;

typedef short bf16x8 __attribute__((ext_vector_type(8)));
typedef float f32x4  __attribute__((ext_vector_type(4)));

/* ---- workspace layout (floats) ---- */
#define WS_Y     0                        /* 8192*128 = 1048576 */
#define WS_HMAX  (WS_Y + 1048576)         /* 8192*64 */
#define WS_HMIN  (WS_HMAX + 524288)
#define WS_P1    (WS_HMIN + 524288)       /* 256*128 */
#define WS_HB    (WS_P1 + 32768)          /* 8192*64 bf16 = 262144 floats */
#define WS_W1B   (WS_HB + 262144)         /* 128*512 bf16 = 32768 floats */
#define WS_P2S   (WS_W1B + 32768)         /* 128*512 */
#define WS_P2Q   (WS_P2S + 65536)
#define WS_SC2   (WS_P2Q + 65536)         /* 512 */
#define WS_SH2   (WS_SC2 + 512)

__device__ __forceinline__ uint f2b(float f) {
    union { float f; uint u; } v; v.f = f;
    return (v.u + 0x7fffu + ((v.u >> 16) & 1u)) >> 16;
}
__device__ __forceinline__ uint2 f4_to_b4(float4 v) {
    uint2 r;
    r.x = f2b(v.x) | (f2b(v.y) << 16);
    r.y = f2b(v.z) | (f2b(v.w) << 16);
    return r;
}
__device__ __forceinline__ bf16x8 u4_to_b8(uint4 v) {
    union { uint4 u; bf16x8 b; } c; c.u = v; return c.b;
}
__device__ __forceinline__ float lrelu(float v) { return v >= 0.f ? v : 0.2f * v; }

__global__ __launch_bounds__(256) void k_fused(
    const float* __restrict__ x,  const int* __restrict__ idx,
    const float* __restrict__ W1, const float* __restrict__ g1,
    const float* __restrict__ b1, const float* __restrict__ W2,
    const float* __restrict__ g2, const float* __restrict__ b2,
    float* __restrict__ out,
    float* __restrict__ Y, float* __restrict__ Hmax, float* __restrict__ Hmin,
    float* __restrict__ P1, ushort* __restrict__ Hb, ushort* __restrict__ W1b,
    float* __restrict__ P2s, float* __restrict__ P2q,
    float* __restrict__ sc2g, float* __restrict__ sh2g)
{
    cg::grid_group grid = cg::this_grid();

    __shared__ __align__(16) ushort sU[144 * 72];   /* sXb[16][72] ++ sWb[128][72] */
    __shared__ float sSc1[64], sSh1[64];
    __shared__ float sRed[512];
    __shared__ float sTmp[256], sTmp2[256];
    __shared__ float sSc2[256], sSh2[256];

    const int t = threadIdx.x, lane = t & 63, w = t >> 6;
    const int bkid = blockIdx.x;
    ushort* sXb = sU;
    ushort* sWb = sU + 16 * 72;

    /* ---------------- A0: W1 -> bf16 (half-split remap) ---------------- */
    {
        const int tid = bkid * 256 + t;
        if (tid < 8192) {
            const int o = tid * 8, j = o >> 9, k = o & 511;
            const float* src = (j < 64) ? &W1[(size_t)j * 1024 + k]
                                        : &W1[(size_t)(j - 64) * 1024 + 512 + k];
            const float4 a  = *(const float4*)src;
            const float4 bb = *(const float4*)(src + 4);
            const uint2 la = f4_to_b4(a), lb = f4_to_b4(bb);
            uint4 v; v.x = la.x; v.y = la.y; v.z = lb.x; v.w = lb.y;
            ((uint4*)W1b)[tid] = v;
        }
    }
    __threadfence();
    grid.sync();

    /* ---------------- A1: Y = x @ W1b^T  (MFMA) ---------------- */
    {
        const int xr_row = t >> 4, xc = t & 15;
        const int wj = t >> 1, wh = t & 1;
        const ushort* pA  = sXb + (lane & 15) * 72 + (lane >> 4) * 8;
        const ushort* pB0 = sWb + (w * 32 + (lane & 15)) * 72 + (lane >> 4) * 8;
        for (int it = 0; it < 2; ++it) {
            const int r0 = (it * 256 + bkid) * 16;
            const size_t xbase = (size_t)(r0 + xr_row) * 512 + xc * 4;
            const size_t wbase = (size_t)wj * 512 + wh * 32;
            f32x4 acc0 = (f32x4){0.f,0.f,0.f,0.f};
            f32x4 acc1 = (f32x4){0.f,0.f,0.f,0.f};
            float4 xr = *(const float4*)&x[xbase];
            uint4 wv0 = *(const uint4*)&W1b[wbase];
            uint4 wv1 = *(const uint4*)&W1b[wbase + 8];
            uint4 wv2 = *(const uint4*)&W1b[wbase + 16];
            uint4 wv3 = *(const uint4*)&W1b[wbase + 24];
            for (int ks = 0; ks < 8; ++ks) {
                __syncthreads();
                *(uint2*)(sXb + xr_row * 72 + xc * 4) = f4_to_b4(xr);
                *(uint4*)(sWb + wj * 72 + wh * 32)      = wv0;
                *(uint4*)(sWb + wj * 72 + wh * 32 + 8)  = wv1;
                *(uint4*)(sWb + wj * 72 + wh * 32 + 16) = wv2;
                *(uint4*)(sWb + wj * 72 + wh * 32 + 24) = wv3;
                __syncthreads();
                if (ks < 7) {
                    const int k0 = (ks + 1) * 64;
                    xr  = *(const float4*)&x[xbase + k0];
                    wv0 = *(const uint4*)&W1b[wbase + k0];
                    wv1 = *(const uint4*)&W1b[wbase + k0 + 8];
                    wv2 = *(const uint4*)&W1b[wbase + k0 + 16];
                    wv3 = *(const uint4*)&W1b[wbase + k0 + 24];
                }
#pragma unroll
                for (int g = 0; g < 2; ++g) {
                    const bf16x8 af  = *(const bf16x8*)(pA + g * 32);
                    const bf16x8 bf0 = *(const bf16x8*)(pB0 + g * 32);
                    const bf16x8 bf1 = *(const bf16x8*)(pB0 + 16 * 72 + g * 32);
                    acc0 = __builtin_amdgcn_mfma_f32_16x16x32_bf16(af, bf0, acc0, 0, 0, 0);
                    acc1 = __builtin_amdgcn_mfma_f32_16x16x32_bf16(af, bf1, acc1, 0, 0, 0);
                }
            }
            const int crow = r0 + (lane >> 4) * 4;
            const int ccol = w * 32 + (lane & 15);
#pragma unroll
            for (int i = 0; i < 4; ++i) {
                Y[(size_t)(crow + i) * 128 + ccol]      = acc0[i];
                Y[(size_t)(crow + i) * 128 + ccol + 16] = acc1[i];
            }
        }
    }
    __threadfence();
    grid.sync();

    /* ---------------- B: gather + max/min + BN1 partials ---------------- */
    {
        const int gw = bkid * 4 + w;
        const int p0 = gw * 8;
        float s_sum = 0.f, s_sq = 0.f;
        for (int pi = 0; pi < 8; ++pi) {
            const int p = p0 + pi;
            const int bb = p >> 10;
            const float ys = Y[(size_t)p * 128 + lane];
            const float zs = Y[(size_t)p * 128 + 64 + lane];
            const float base = zs - ys;
            float hmx = -INFINITY, hmn = INFINITY;
            const int* ip = &idx[p * 20];
#pragma unroll
            for (int k = 0; k < 20; ++k) {
                const int j = ip[k];
                const float yg = Y[((size_t)(bb * 1024 + j)) * 128 + lane];
                const float h = yg + base;
                s_sum += h; s_sq += h * h;
                hmx = fmaxf(hmx, h); hmn = fminf(hmn, h);
            }
            Hmax[(size_t)p * 64 + lane] = hmx;
            Hmin[(size_t)p * 64 + lane] = hmn;
        }
        sRed[w * 128 + lane]      = s_sum;
        sRed[w * 128 + 64 + lane] = s_sq;
        __syncthreads();
        if (t < 128)
            P1[(size_t)bkid * 128 + t] = sRed[t] + sRed[128 + t] + sRed[256 + t] + sRed[384 + t];
    }
    __threadfence();
    grid.sync();

    /* ---------------- C: BN1 stats (redundant per block -> LDS) ---------------- */
    {
        const int col = t & 127, part = t >> 7;
        float s = 0.f;
        for (int i = 0; i < 128; ++i)
            s += P1[(size_t)(part * 128 + i) * 128 + col];
        sTmp[t] = s;
        __syncthreads();
        if (t < 128) sRed[t] = sTmp[t] + sTmp[t + 128];
        __syncthreads();
        if (t < 64) {
            const float inv = 1.f / 163840.f;     /* 8192*20 */
            const float mu  = sRed[t] * inv;
            const float var = sRed[t + 64] * inv - mu * mu;
            const float rs  = rsqrtf(var + 1e-5f);
            const float sc  = g1[t] * rs;
            sSc1[t] = sc;
            sSh1[t] = b1[t] - mu * sc;
        }
        __syncthreads();
    }

    /* ---------------- D: hbn (in-reg) + Hb write + qsum MFMA ---------------- */
    {
        const int rtile = bkid >> 1, half = bkid & 1;
        const int r0 = rtile * 64;
        const int dsub = half * 256 + w * 64;
        const int q = lane >> 4, s = lane & 15;
        const int mc0 = q * 8;

        bf16x8 bfr[4][2];
#pragma unroll
        for (int f = 0; f < 4; ++f) {
            const int d = dsub + f * 16 + s;
#pragma unroll
            for (int g = 0; g < 2; ++g) {
                const float4 wa = *(const float4*)&W2[(size_t)d * 64 + mc0 + g * 32];
                const float4 wb = *(const float4*)&W2[(size_t)d * 64 + mc0 + g * 32 + 4];
                const uint2 lo = f4_to_b4(wa), hi = f4_to_b4(wb);
                uint4 v; v.x = lo.x; v.y = lo.y; v.z = hi.x; v.w = hi.y;
                bfr[f][g] = u4_to_b8(v);
            }
        }
        f32x4 acc[4][4];
#pragma unroll
        for (int rt = 0; rt < 4; ++rt)
#pragma unroll
            for (int f = 0; f < 4; ++f) acc[rt][f] = (f32x4){0.f,0.f,0.f,0.f};

#pragma unroll
        for (int rt = 0; rt < 4; ++rt) {
            const int row = r0 + rt * 16 + s;
#pragma unroll
            for (int g = 0; g < 2; ++g) {
                const int mc = mc0 + g * 32;
                const size_t base = (size_t)row * 64 + mc;
                const float4 hx0 = *(const float4*)&Hmax[base];
                const float4 hx1 = *(const float4*)&Hmax[base + 4];
                const float4 hn0 = *(const float4*)&Hmin[base];
                const float4 hn1 = *(const float4*)&Hmin[base + 4];
                float v[8];
#pragma unroll
                for (int i = 0; i < 4; ++i) {
                    const float c0 = sSc1[mc + i],     h0 = sSh1[mc + i];
                    const float c4 = sSc1[mc + 4 + i], h4 = sSh1[mc + 4 + i];
                    const float a0 = c0 >= 0.f ? ((const float*)&hx0)[i] : ((const float*)&hn0)[i];
                    const float a4 = c4 >= 0.f ? ((const float*)&hx1)[i] : ((const float*)&hn1)[i];
                    v[i]     = lrelu(a0 * c0 + h0);
                    v[i + 4] = lrelu(a4 * c4 + h4);
                }
                uint4 pk;
                pk.x = f2b(v[0]) | (f2b(v[1]) << 16);
                pk.y = f2b(v[2]) | (f2b(v[3]) << 16);
                pk.z = f2b(v[4]) | (f2b(v[5]) << 16);
                pk.w = f2b(v[6]) | (f2b(v[7]) << 16);
                if (half == 0) *(uint4*)&Hb[base] = pk;
                const bf16x8 af = u4_to_b8(pk);
#pragma unroll
                for (int f = 0; f < 4; ++f)
                    acc[rt][f] = __builtin_amdgcn_mfma_f32_16x16x32_bf16(af, bfr[f][g], acc[rt][f], 0, 0, 0);
            }
        }
#pragma unroll
        for (int f = 0; f < 4; ++f) {
            float ss = 0.f, qq = 0.f;
#pragma unroll
            for (int rt = 0; rt < 4; ++rt)
#pragma unroll
                for (int i = 0; i < 4; ++i) {
                    const float vv = acc[rt][f][i];
                    ss += vv; qq += vv * vv;
                }
            ss += __shfl_xor(ss, 16); ss += __shfl_xor(ss, 32);
            qq += __shfl_xor(qq, 16); qq += __shfl_xor(qq, 32);
            if (lane < 16) {
                const int d = dsub + f * 16 + s;
                P2s[(size_t)rtile * 512 + d] = ss;
                P2q[(size_t)rtile * 512 + d] = qq;
            }
        }
    }
    __threadfence();
    grid.sync();

    /* ---------------- E: BN2 stats (2 channels per block) ---------------- */
    {
        const int colSel = t >> 7, row = t & 127;
        const int col = bkid * 2 + colSel;
        sTmp[t]  = P2s[(size_t)row * 512 + col];
        sTmp2[t] = P2q[(size_t)row * 512 + col];
        __syncthreads();
#pragma unroll
        for (int st = 64; st >= 1; st >>= 1) {
            if (row < st) {
                sTmp[t]  += sTmp[t + st];
                sTmp2[t] += sTmp2[t + st];
            }
            __syncthreads();
        }
        if (row == 0) {
            const float inv = 1.f / 8192.f;
            const float ss = sTmp[colSel * 128], qq = sTmp2[colSel * 128];
            const float mu  = ss * inv;
            const float var = qq * inv - mu * mu;
            const float rs  = rsqrtf(var + 1e-5f);
            const float sc  = g2[col] * rs;
            sc2g[col] = sc;
            sh2g[col] = b2[col] - mu * sc;
        }
    }
    __threadfence();
    grid.sync();

    /* ---------------- F: h2 recompute + BN2 + leaky -> out ---------------- */
    {
        const int rtile = bkid >> 1, half = bkid & 1;
        const int r0 = rtile * 64;
        const int dsub = half * 256 + w * 64;
        const int q = lane >> 4, s = lane & 15;
        const int mc0 = q * 8;

        sSc2[t] = sc2g[half * 256 + t];
        sSh2[t] = sh2g[half * 256 + t];
        __syncthreads();

        bf16x8 bfr[4][2];
#pragma unroll
        for (int f = 0; f < 4; ++f) {
            const int d = dsub + f * 16 + s;
#pragma unroll
            for (int g = 0; g < 2; ++g) {
                const float4 wa = *(const float4*)&W2[(size_t)d * 64 + mc0 + g * 32];
                const float4 wb = *(const float4*)&W2[(size_t)d * 64 + mc0 + g * 32 + 4];
                const uint2 lo = f4_to_b4(wa), hi = f4_to_b4(wb);
                uint4 v; v.x = lo.x; v.y = lo.y; v.z = hi.x; v.w = hi.y;
                bfr[f][g] = u4_to_b8(v);
            }
        }
        f32x4 acc[4][4];
#pragma unroll
        for (int rt = 0; rt < 4; ++rt)
#pragma unroll
            for (int f = 0; f < 4; ++f) acc[rt][f] = (f32x4){0.f,0.f,0.f,0.f};

#pragma unroll
        for (int rt = 0; rt < 4; ++rt) {
            const int row = r0 + rt * 16 + s;
#pragma unroll
            for (int g = 0; g < 2; ++g) {
                const bf16x8 af = *(const bf16x8*)&Hb[(size_t)row * 64 + mc0 + g * 32];
#pragma unroll
                for (int f = 0; f < 4; ++f)
                    acc[rt][f] = __builtin_amdgcn_mfma_f32_16x16x32_bf16(af, bfr[f][g], acc[rt][f], 0, 0, 0);
            }
        }
#pragma unroll
        for (int rt = 0; rt < 4; ++rt)
#pragma unroll
            for (int f = 0; f < 4; ++f) {
                const int dl = w * 64 + f * 16 + s;
                const float c2 = sSc2[dl], h2 = sSh2[dl];
                const int d = dsub + f * 16 + s;
#pragma unroll
                for (int i = 0; i < 4; ++i) {
                    const float vv = lrelu(acc[rt][f][i] * c2 + h2);
                    out[(size_t)(r0 + rt * 16 + q * 4 + i) * 512 + d] = vv;
                }
            }
    }
}

/* ------------------------------------------------------------------ */
extern "C" void kernel_launch(void* const* d_in, const int* in_sizes, int n_in,
                              void* d_out, int out_size, void* d_ws, size_t ws_size,
                              hipStream_t stream) {
    const float* x   = (const float*)d_in[0];
    const int*   idx = (const int*)d_in[1];
    const float* W1  = (const float*)d_in[2];
    const float* g1  = (const float*)d_in[3];
    const float* b1  = (const float*)d_in[4];
    const float* W2  = (const float*)d_in[5];
    const float* g2  = (const float*)d_in[6];
    const float* b2  = (const float*)d_in[7];
    float* out = (float*)d_out;
    float* ws  = (float*)d_ws;

    float*  Y    = ws + WS_Y;
    float*  Hmax = ws + WS_HMAX;
    float*  Hmin = ws + WS_HMIN;
    float*  P1   = ws + WS_P1;
    ushort* Hb   = (ushort*)(ws + WS_HB);
    ushort* W1b  = (ushort*)(ws + WS_W1B);
    float*  P2s  = ws + WS_P2S;
    float*  P2q  = ws + WS_P2Q;
    float*  sc2g = ws + WS_SC2;
    float*  sh2g = ws + WS_SH2;

    void* args[] = {
        (void*)&x, (void*)&idx, (void*)&W1, (void*)&g1, (void*)&b1,
        (void*)&W2, (void*)&g2, (void*)&b2, (void*)&out,
        (void*)&Y, (void*)&Hmax, (void*)&Hmin, (void*)&P1, (void*)&Hb,
        (void*)&W1b, (void*)&P2s, (void*)&P2q, (void*)&sc2g, (void*)&sh2g
    };
    hipLaunchCooperativeKernel((void*)k_fused, dim3(256), dim3(256), args, 0, stream);
}

// Round 5
// 66.860 us; speedup vs baseline: 4.4848x; 4.4848x over previous
//
#include <hip/hip_runtime.h>
#include <math.h>

#define B_ 8
#define N_ 1024
#define C_ 512
#define K_ 20
#define M_ 64
#define R_ (B_*N_)   /* 8192 points */

typedef short bf16x8 __attribute__((ext_vector_type(8)));
typedef float f32x4  __attribute__((ext_vector_type(4)));

/* ---- workspace layout (floats) ---- */
#define WS_Y     0                        /* R_*128 fp32 = 1048576 */
#define WS_HMAX  (WS_Y + R_*128)          /* R_*64 */
#define WS_HMIN  (WS_HMAX + R_*64)
#define WS_P1A   (WS_HMIN + R_*64)        /* 128: sum[64] ++ sumsq[64] */
#define WS_P2A   (WS_P1A + 128)           /* 1024: sum[512] ++ sumsq[512] */
#define WS_HB    (WS_P2A + 1024)          /* R_*64 bf16 = 262144 floats */
#define WS_W1B   (WS_HB + R_*32)          /* 128*512 bf16 = 32768 floats */
#define WS_W2B   (WS_W1B + 32768)         /* 512*64 bf16 = 16384 floats */

__device__ __forceinline__ uint f2b(float f) {
    union { float f; uint u; } v; v.f = f;
    return (v.u + 0x7fffu + ((v.u >> 16) & 1u)) >> 16;
}
__device__ __forceinline__ uint2 f4_to_b4(float4 v) {
    uint2 r;
    r.x = f2b(v.x) | (f2b(v.y) << 16);
    r.y = f2b(v.z) | (f2b(v.w) << 16);
    return r;
}
__device__ __forceinline__ float lrelu(float v) { return v >= 0.f ? v : 0.2f * v; }

/* ------------------------------------------------------------------ */
/* prep: W1->bf16 (half-split remap), W2->bf16, zero atomic accumulators */
__global__ __launch_bounds__(256) void k_prep(const float* __restrict__ W1,
                                              const float* __restrict__ W2,
                                              ushort* __restrict__ W1b,
                                              ushort* __restrict__ W2b,
                                              float* __restrict__ P1a,
                                              float* __restrict__ P2a) {
    const int tid = blockIdx.x * 256 + threadIdx.x;
    if (tid < 8192) {                       /* W1b: 128 rows x 512 */
        const int o = tid * 8, j = o >> 9, k = o & 511;
        const float* src = (j < 64) ? &W1[(size_t)j * 1024 + k]
                                    : &W1[(size_t)(j - 64) * 1024 + 512 + k];
        const float4 a = *(const float4*)src;
        const float4 b = *(const float4*)(src + 4);
        const uint2 la = f4_to_b4(a), lb = f4_to_b4(b);
        uint4 v; v.x = la.x; v.y = la.y; v.z = lb.x; v.w = lb.y;
        ((uint4*)W1b)[tid] = v;
    } else if (tid < 12288) {               /* W2b: 512 rows x 64 */
        const int t2 = tid - 8192, o = t2 * 8;
        const float4 a = *(const float4*)&W2[o];
        const float4 b = *(const float4*)&W2[o + 4];
        const uint2 la = f4_to_b4(a), lb = f4_to_b4(b);
        uint4 v; v.x = la.x; v.y = la.y; v.z = lb.x; v.w = lb.y;
        ((uint4*)W2b)[t2] = v;
    } else if (tid < 13312) {
        P2a[tid - 12288] = 0.f;
    } else if (tid < 13440) {
        P1a[tid - 13312] = 0.f;
    }
}

/* ------------------------------------------------------------------ */
/* Y[r][j] = x[r] . W1b[j]   (16 rows x 128 cols per block, 512 blocks) */
__global__ __launch_bounds__(256) void k_yz(const float* __restrict__ x,
                                            const ushort* __restrict__ W1b,
                                            float* __restrict__ Y) {
    __shared__ __align__(16) ushort sXb[16][72];
    __shared__ __align__(16) ushort sWb[128][72];
    const int t = threadIdx.x, lane = t & 63, w = t >> 6;
    const int r0 = blockIdx.x * 16;
    const int xr_row = t >> 4, xc = t & 15;
    const int wj = t >> 1, wh = t & 1;
    const size_t xbase = (size_t)(r0 + xr_row) * 512 + xc * 4;
    const size_t wbase = (size_t)wj * 512 + wh * 32;

    f32x4 acc[2];
    acc[0] = (f32x4){0.f, 0.f, 0.f, 0.f};
    acc[1] = (f32x4){0.f, 0.f, 0.f, 0.f};

    const ushort* pA  = &sXb[lane & 15][(lane >> 4) * 8];
    const ushort* pB0 = &sWb[w * 32 + (lane & 15)][(lane >> 4) * 8];

    float4 xr = *(const float4*)&x[xbase];
    uint4 wv[4];
#pragma unroll
    for (int i = 0; i < 4; ++i) wv[i] = *(const uint4*)&W1b[wbase + i * 8];

    for (int ks = 0; ks < 8; ++ks) {
        __syncthreads();
        *(uint2*)&sXb[xr_row][xc * 4] = f4_to_b4(xr);
#pragma unroll
        for (int i = 0; i < 4; ++i)
            *(uint4*)&sWb[wj][wh * 32 + i * 8] = wv[i];
        __syncthreads();

        if (ks < 7) {
            const int k0 = (ks + 1) * 64;
            xr = *(const float4*)&x[xbase + k0];
#pragma unroll
            for (int i = 0; i < 4; ++i)
                wv[i] = *(const uint4*)&W1b[wbase + k0 + i * 8];
        }

#pragma unroll
        for (int g = 0; g < 2; ++g) {
            const bf16x8 af = *(const bf16x8*)(pA + g * 32);
#pragma unroll
            for (int jj = 0; jj < 2; ++jj) {
                const bf16x8 bf = *(const bf16x8*)(pB0 + jj * 16 * 72 + g * 32);
                acc[jj] = __builtin_amdgcn_mfma_f32_16x16x32_bf16(af, bf, acc[jj], 0, 0, 0);
            }
        }
    }

    const int crow = r0 + (lane >> 4) * 4;
    const int ccol = w * 32 + (lane & 15);
#pragma unroll
    for (int jj = 0; jj < 2; ++jj)
#pragma unroll
        for (int i = 0; i < 4; ++i)
            Y[(size_t)(crow + i) * 128 + ccol + jj * 16] = acc[jj][i];
}

/* ------------------------------------------------------------------ */
/* gather + per-point max/min + BN1 partials -> atomics. 512 blocks. */
__global__ __launch_bounds__(256) void k_gather(const float* __restrict__ Y,
                                                const int* __restrict__ idx,
                                                float* __restrict__ Hmax,
                                                float* __restrict__ Hmin,
                                                float* __restrict__ P1a) {
    __shared__ float sRed[4][128];
    const int t = threadIdx.x;
    const int w = t >> 6, lane = t & 63;
    const int p0 = blockIdx.x * 16 + w * 4;
    float s_sum = 0.f, s_sq = 0.f;
#pragma unroll
    for (int i = 0; i < 4; ++i) {
        const int p = p0 + i;
        const int b = p >> 10;
        const float ys = Y[(size_t)p * 128 + lane];
        const float zs = Y[(size_t)p * 128 + 64 + lane];
        const float base = zs - ys;
        float hmx = -INFINITY, hmn = INFINITY;
        const int* ip = &idx[p * K_];
#pragma unroll
        for (int k = 0; k < K_; ++k) {
            const int j = ip[k];
            const float yg = Y[((size_t)(b * N_ + j)) * 128 + lane];
            const float h = yg + base;
            s_sum += h;
            s_sq  += h * h;
            hmx = fmaxf(hmx, h);
            hmn = fminf(hmn, h);
        }
        Hmax[(size_t)p * 64 + lane] = hmx;
        Hmin[(size_t)p * 64 + lane] = hmn;
    }
    sRed[w][lane]      = s_sum;
    sRed[w][64 + lane] = s_sq;
    __syncthreads();
    if (t < 128) {
        const float v = sRed[0][t] + sRed[1][t] + sRed[2][t] + sRed[3][t];
        atomicAdd(&P1a[t], v);
    }
}

/* ------------------------------------------------------------------ */
/* qsum: finalize BN1 (from P1a), compute hbn in-reg, write Hb (half 0),
   h2 = hbn @ W2b^T MFMA, per-d sum/sumsq -> atomics. grid (128,2). */
__global__ __launch_bounds__(256) void k_qsum(const float* __restrict__ Hmax,
                                              const float* __restrict__ Hmin,
                                              const float* __restrict__ P1a,
                                              const float* __restrict__ g1,
                                              const float* __restrict__ b1,
                                              const ushort* __restrict__ W2b,
                                              ushort* __restrict__ Hb,
                                              float* __restrict__ P2a) {
    __shared__ float sSc1[64], sSh1[64];
    const int t = threadIdx.x, lane = t & 63, w = t >> 6;
    if (t < 64) {
        const float inv = 1.f / (float)(R_ * K_);
        const float mu  = P1a[t] * inv;
        const float var = P1a[64 + t] * inv - mu * mu;
        const float rs  = rsqrtf(var + 1e-5f);
        const float sc  = g1[t] * rs;
        sSc1[t] = sc;
        sSh1[t] = b1[t] - mu * sc;
    }
    __syncthreads();

    const int rtile = blockIdx.x, half = blockIdx.y;
    const int r0 = rtile * 64;
    const int dsub = half * 256 + w * 64;
    const int qd = lane >> 4, s = lane & 15;
    const int mc0 = qd * 8;

    bf16x8 bfr[4][2];
#pragma unroll
    for (int f = 0; f < 4; ++f)
#pragma unroll
        for (int g = 0; g < 2; ++g)
            bfr[f][g] = *(const bf16x8*)&W2b[(size_t)(dsub + f * 16 + s) * 64 + mc0 + g * 32];

    f32x4 acc[4][4];
#pragma unroll
    for (int rt = 0; rt < 4; ++rt)
#pragma unroll
        for (int f = 0; f < 4; ++f) acc[rt][f] = (f32x4){0.f,0.f,0.f,0.f};

#pragma unroll
    for (int rt = 0; rt < 4; ++rt) {
        const int row = r0 + rt * 16 + s;
#pragma unroll
        for (int g = 0; g < 2; ++g) {
            const int mc = mc0 + g * 32;
            const size_t base = (size_t)row * 64 + mc;
            const float4 hx0 = *(const float4*)&Hmax[base];
            const float4 hx1 = *(const float4*)&Hmax[base + 4];
            const float4 hn0 = *(const float4*)&Hmin[base];
            const float4 hn1 = *(const float4*)&Hmin[base + 4];
            float v[8];
#pragma unroll
            for (int i = 0; i < 4; ++i) {
                const float c0 = sSc1[mc + i],     h0 = sSh1[mc + i];
                const float c4 = sSc1[mc + 4 + i], h4 = sSh1[mc + 4 + i];
                const float a0 = c0 >= 0.f ? ((const float*)&hx0)[i] : ((const float*)&hn0)[i];
                const float a4 = c4 >= 0.f ? ((const float*)&hx1)[i] : ((const float*)&hn1)[i];
                v[i]     = lrelu(a0 * c0 + h0);
                v[i + 4] = lrelu(a4 * c4 + h4);
            }
            uint4 pk;
            pk.x = f2b(v[0]) | (f2b(v[1]) << 16);
            pk.y = f2b(v[2]) | (f2b(v[3]) << 16);
            pk.z = f2b(v[4]) | (f2b(v[5]) << 16);
            pk.w = f2b(v[6]) | (f2b(v[7]) << 16);
            if (half == 0) *(uint4*)&Hb[base] = pk;
            union { uint4 u; bf16x8 b; } cv; cv.u = pk;
#pragma unroll
            for (int f = 0; f < 4; ++f)
                acc[rt][f] = __builtin_amdgcn_mfma_f32_16x16x32_bf16(cv.b, bfr[f][g], acc[rt][f], 0, 0, 0);
        }
    }

#pragma unroll
    for (int f = 0; f < 4; ++f) {
        float ss = 0.f, qq = 0.f;
#pragma unroll
        for (int rt = 0; rt < 4; ++rt)
#pragma unroll
            for (int i = 0; i < 4; ++i) {
                const float vv = acc[rt][f][i];
                ss += vv; qq += vv * vv;
            }
        ss += __shfl_xor(ss, 16); ss += __shfl_xor(ss, 32);
        qq += __shfl_xor(qq, 16); qq += __shfl_xor(qq, 32);
        if (lane < 16) {
            const int d = dsub + f * 16 + s;
            atomicAdd(&P2a[d], ss);
            atomicAdd(&P2a[512 + d], qq);
        }
    }
}

/* ------------------------------------------------------------------ */
/* out: finalize BN2 (from P2a), h2 recompute MFMA, BN2+leaky, write. */
__global__ __launch_bounds__(256) void k_out(const ushort* __restrict__ Hb,
                                             const ushort* __restrict__ W2b,
                                             const float* __restrict__ P2a,
                                             const float* __restrict__ g2,
                                             const float* __restrict__ b2,
                                             float* __restrict__ out) {
    __shared__ float sSc2[256], sSh2[256];
    const int t = threadIdx.x, lane = t & 63, w = t >> 6;
    const int rtile = blockIdx.x, half = blockIdx.y;
    {
        const int d = half * 256 + t;
        const float inv = 1.f / (float)R_;
        const float mu  = P2a[d] * inv;
        const float var = P2a[512 + d] * inv - mu * mu;
        const float rs  = rsqrtf(var + 1e-5f);
        const float sc  = g2[d] * rs;
        sSc2[t] = sc;
        sSh2[t] = b2[d] - mu * sc;
    }
    __syncthreads();

    const int r0 = rtile * 64;
    const int dsub = half * 256 + w * 64;
    const int qd = lane >> 4, s = lane & 15;
    const int mc0 = qd * 8;

    bf16x8 bfr[4][2];
#pragma unroll
    for (int f = 0; f < 4; ++f)
#pragma unroll
        for (int g = 0; g < 2; ++g)
            bfr[f][g] = *(const bf16x8*)&W2b[(size_t)(dsub + f * 16 + s) * 64 + mc0 + g * 32];

    f32x4 acc[4][4];
#pragma unroll
    for (int rt = 0; rt < 4; ++rt)
#pragma unroll
        for (int f = 0; f < 4; ++f) acc[rt][f] = (f32x4){0.f,0.f,0.f,0.f};

#pragma unroll
    for (int rt = 0; rt < 4; ++rt) {
        const int row = r0 + rt * 16 + s;
#pragma unroll
        for (int g = 0; g < 2; ++g) {
            const bf16x8 af = *(const bf16x8*)&Hb[(size_t)row * 64 + mc0 + g * 32];
#pragma unroll
            for (int f = 0; f < 4; ++f)
                acc[rt][f] = __builtin_amdgcn_mfma_f32_16x16x32_bf16(af, bfr[f][g], acc[rt][f], 0, 0, 0);
        }
    }

#pragma unroll
    for (int rt = 0; rt < 4; ++rt)
#pragma unroll
        for (int f = 0; f < 4; ++f) {
            const int dl = w * 64 + f * 16 + s;
            const float c2 = sSc2[dl], h2 = sSh2[dl];
            const int d = dsub + f * 16 + s;
#pragma unroll
            for (int i = 0; i < 4; ++i) {
                const float vv = lrelu(acc[rt][f][i] * c2 + h2);
                out[(size_t)(r0 + rt * 16 + qd * 4 + i) * 512 + d] = vv;
            }
        }
}

/* ------------------------------------------------------------------ */
extern "C" void kernel_launch(void* const* d_in, const int* in_sizes, int n_in,
                              void* d_out, int out_size, void* d_ws, size_t ws_size,
                              hipStream_t stream) {
    const float* x   = (const float*)d_in[0];
    const int*   idx = (const int*)d_in[1];
    const float* W1  = (const float*)d_in[2];
    const float* g1  = (const float*)d_in[3];
    const float* b1  = (const float*)d_in[4];
    const float* W2  = (const float*)d_in[5];
    const float* g2  = (const float*)d_in[6];
    const float* b2  = (const float*)d_in[7];
    float* out = (float*)d_out;
    float* ws  = (float*)d_ws;

    float*  Y    = ws + WS_Y;
    float*  Hmax = ws + WS_HMAX;
    float*  Hmin = ws + WS_HMIN;
    float*  P1a  = ws + WS_P1A;
    float*  P2a  = ws + WS_P2A;
    ushort* Hb   = (ushort*)(ws + WS_HB);
    ushort* W1b  = (ushort*)(ws + WS_W1B);
    ushort* W2b  = (ushort*)(ws + WS_W2B);

    k_prep  <<<dim3(56),      dim3(256), 0, stream>>>(W1, W2, W1b, W2b, P1a, P2a);
    k_yz    <<<dim3(R_ / 16), dim3(256), 0, stream>>>(x, W1b, Y);
    k_gather<<<dim3(R_ / 16), dim3(256), 0, stream>>>(Y, idx, Hmax, Hmin, P1a);
    k_qsum  <<<dim3(128, 2),  dim3(256), 0, stream>>>(Hmax, Hmin, P1a, g1, b1, W2b, Hb, P2a);
    k_out   <<<dim3(128, 2),  dim3(256), 0, stream>>>(Hb, W2b, P2a, g2, b2, out);
}

// Round 6
// 51.608 us; speedup vs baseline: 5.8102x; 1.2955x over previous
//
#include <hip/hip_runtime.h>
#include <math.h>

#define B_ 8
#define N_ 1024
#define C_ 512
#define K_ 20
#define M_ 64
#define R_ (B_*N_)   /* 8192 points */

typedef short bf16x8 __attribute__((ext_vector_type(8)));
typedef float f32x4  __attribute__((ext_vector_type(4)));

/* ---- workspace layout (floats) ---- */
#define WS_Y     0                        /* bf16 Y[R_][128] = R_*64 floats */
#define WS_HMM   (WS_Y + R_*64)           /* uint HMM[R_][64] (hmax|hmin bf16) */
#define WS_P1A   (WS_HMM + R_*64)         /* 128: sum[64] ++ sumsq[64] */
#define WS_P2A   (WS_P1A + 128)           /* 1024: sum[512] ++ sumsq[512] */
#define WS_HB    (WS_P2A + 1024)          /* bf16 Hb[R_][64] = R_*32 floats */
#define WS_W1B   (WS_HB + R_*32)          /* bf16 128x512 = 32768 floats */
#define WS_W2B   (WS_W1B + 32768)         /* bf16 512x64 = 16384 floats */

__device__ __forceinline__ uint f2b(float f) {
    union { float f; uint u; } v; v.f = f;
    return (v.u + 0x7fffu + ((v.u >> 16) & 1u)) >> 16;
}
__device__ __forceinline__ uint2 f4_to_b4(float4 v) {
    uint2 r;
    r.x = f2b(v.x) | (f2b(v.y) << 16);
    r.y = f2b(v.z) | (f2b(v.w) << 16);
    return r;
}
__device__ __forceinline__ float b2f(ushort u) {
    union { uint u; float f; } v; v.u = (uint)u << 16; return v.f;
}
__device__ __forceinline__ float bits2f(uint u) {
    union { uint u; float f; } v; v.u = u; return v.f;
}
__device__ __forceinline__ float lrelu(float v) { return v >= 0.f ? v : 0.2f * v; }

/* ------------------------------------------------------------------ */
/* prep: W1->bf16 (half-split remap), W2->bf16, zero atomic accumulators */
__global__ __launch_bounds__(256) void k_prep(const float* __restrict__ W1,
                                              const float* __restrict__ W2,
                                              ushort* __restrict__ W1b,
                                              ushort* __restrict__ W2b,
                                              float* __restrict__ P1a,
                                              float* __restrict__ P2a) {
    const int tid = blockIdx.x * 256 + threadIdx.x;
    if (tid < 8192) {                       /* W1b: 128 rows x 512 */
        const int o = tid * 8, j = o >> 9, k = o & 511;
        const float* src = (j < 64) ? &W1[(size_t)j * 1024 + k]
                                    : &W1[(size_t)(j - 64) * 1024 + 512 + k];
        const float4 a = *(const float4*)src;
        const float4 b = *(const float4*)(src + 4);
        const uint2 la = f4_to_b4(a), lb = f4_to_b4(b);
        uint4 v; v.x = la.x; v.y = la.y; v.z = lb.x; v.w = lb.y;
        ((uint4*)W1b)[tid] = v;
    } else if (tid < 12288) {               /* W2b: 512 rows x 64 */
        const int t2 = tid - 8192, o = t2 * 8;
        const float4 a = *(const float4*)&W2[o];
        const float4 b = *(const float4*)&W2[o + 4];
        const uint2 la = f4_to_b4(a), lb = f4_to_b4(b);
        uint4 v; v.x = la.x; v.y = la.y; v.z = lb.x; v.w = lb.y;
        ((uint4*)W2b)[t2] = v;
    } else if (tid < 13312) {
        P2a[tid - 12288] = 0.f;
    } else if (tid < 13440) {
        P1a[tid - 13312] = 0.f;
    }
}

/* ------------------------------------------------------------------ */
/* Y = x @ W1b^T.  256 blocks x 32 rows.  W1b staged ONCE in LDS
   (XOR-swizzled); x A-fragments loaded straight to registers. */
__global__ __launch_bounds__(256) void k_yz(const float* __restrict__ x,
                                            const ushort* __restrict__ W1b,
                                            ushort* __restrict__ Y) {
    __shared__ __align__(16) ushort sWb[65536];   /* 128 KiB */
    const int t = threadIdx.x, lane = t & 63, w = t >> 6;
    const int wr = w >> 1, wc = w & 1;
    const int r0 = blockIdx.x * 32;

    /* stage all of W1b (128x512 bf16), swizzle byte^=(j&7)<<4 */
#pragma unroll
    for (int i = 0; i < 32; ++i) {
        const int f = i * 256 + t;
        const int j = f >> 6, kq = f & 63;
        const uint4 v = ((const uint4*)W1b)[f];
        const int off = j * 1024 + ((kq * 16) ^ ((j & 7) << 4));
        *(uint4*)((char*)sWb + off) = v;
    }

    /* load ALL x fragments for this wave upfront (8 ks x 2 g x 2 float4) */
    const int arow = r0 + wr * 16 + (lane & 15);
    const size_t xbase = (size_t)arow * 512 + ((lane >> 4) * 8);
    float4 xr[8][4];
#pragma unroll
    for (int ks = 0; ks < 8; ++ks) {
        const size_t b = xbase + ks * 64;
        xr[ks][0] = *(const float4*)&x[b];
        xr[ks][1] = *(const float4*)&x[b + 4];
        xr[ks][2] = *(const float4*)&x[b + 32];
        xr[ks][3] = *(const float4*)&x[b + 36];
    }

    f32x4 acc[4];
#pragma unroll
    for (int jj = 0; jj < 4; ++jj) acc[jj] = (f32x4){0.f, 0.f, 0.f, 0.f};

    __syncthreads();

    const int jbase = wc * 64 + (lane & 15);
    const int kb_base = (lane >> 4) * 16;    /* byte offset of 8-elem slice */

#pragma unroll
    for (int ks = 0; ks < 8; ++ks) {
        const uint2 c00 = f4_to_b4(xr[ks][0]), c01 = f4_to_b4(xr[ks][1]);
        const uint2 c10 = f4_to_b4(xr[ks][2]), c11 = f4_to_b4(xr[ks][3]);
        union { uint4 u; bf16x8 b; } A0, A1;
        A0.u.x = c00.x; A0.u.y = c00.y; A0.u.z = c01.x; A0.u.w = c01.y;
        A1.u.x = c10.x; A1.u.y = c10.y; A1.u.z = c11.x; A1.u.w = c11.y;
        const int k0 = ks * 128 + kb_base;
#pragma unroll
        for (int jj = 0; jj < 4; ++jj) {
            const int jrow = jbase + jj * 16;
            const int rowoff = jrow * 1024;
            const int sw = (jrow & 7) << 4;
            const bf16x8 B0 = *(const bf16x8*)((char*)sWb + rowoff + (k0 ^ sw));
            const bf16x8 B1 = *(const bf16x8*)((char*)sWb + rowoff + ((k0 + 64) ^ sw));
            acc[jj] = __builtin_amdgcn_mfma_f32_16x16x32_bf16(A0.b, B0, acc[jj], 0, 0, 0);
            acc[jj] = __builtin_amdgcn_mfma_f32_16x16x32_bf16(A1.b, B1, acc[jj], 0, 0, 0);
        }
    }

    /* C layout: col = lane&15, row = (lane>>4)*4 + i */
    const int crow = r0 + wr * 16 + (lane >> 4) * 4;
    const int ccol = wc * 64 + (lane & 15);
#pragma unroll
    for (int jj = 0; jj < 4; ++jj)
#pragma unroll
        for (int i = 0; i < 4; ++i)
            Y[(size_t)(crow + i) * 128 + ccol + jj * 16] = (ushort)f2b(acc[jj][i]);
}

/* ------------------------------------------------------------------ */
/* gather (bf16 Y) + per-point max/min (packed bf16) + BN1 partials. */
__global__ __launch_bounds__(256) void k_gather(const ushort* __restrict__ Y,
                                                const int* __restrict__ idx,
                                                uint* __restrict__ HMM,
                                                float* __restrict__ P1a) {
    __shared__ float sRed[4][128];
    const int t = threadIdx.x;
    const int w = t >> 6, lane = t & 63;
    const int p0 = blockIdx.x * 16 + w * 4;
    float s_sum = 0.f, s_sq = 0.f;
#pragma unroll
    for (int i = 0; i < 4; ++i) {
        const int p = p0 + i;
        const int b = p >> 10;
        const float ys = b2f(Y[(size_t)p * 128 + lane]);
        const float zs = b2f(Y[(size_t)p * 128 + 64 + lane]);
        const float base = zs - ys;
        float hmx = -INFINITY, hmn = INFINITY;
        const int* ip = &idx[p * K_];
#pragma unroll
        for (int k = 0; k < K_; ++k) {
            const int j = ip[k];
            const float yg = b2f(Y[((size_t)(b * N_ + j)) * 128 + lane]);
            const float h = yg + base;
            s_sum += h;
            s_sq  += h * h;
            hmx = fmaxf(hmx, h);
            hmn = fminf(hmn, h);
        }
        HMM[(size_t)p * 64 + lane] = f2b(hmx) | (f2b(hmn) << 16);
    }
    sRed[w][lane]      = s_sum;
    sRed[w][64 + lane] = s_sq;
    __syncthreads();
    if (t < 128) {
        const float v = sRed[0][t] + sRed[1][t] + sRed[2][t] + sRed[3][t];
        atomicAdd(&P1a[t], v);
    }
}

/* ------------------------------------------------------------------ */
/* qsum: finalize BN1, hbn in-reg, write Hb (half 0), MFMA stats -> atomics */
__global__ __launch_bounds__(256) void k_qsum(const uint* __restrict__ HMM,
                                              const float* __restrict__ P1a,
                                              const float* __restrict__ g1,
                                              const float* __restrict__ b1,
                                              const ushort* __restrict__ W2b,
                                              ushort* __restrict__ Hb,
                                              float* __restrict__ P2a) {
    __shared__ float sSc1[64], sSh1[64];
    const int t = threadIdx.x, lane = t & 63, w = t >> 6;
    if (t < 64) {
        const float inv = 1.f / (float)(R_ * K_);
        const float mu  = P1a[t] * inv;
        const float var = P1a[64 + t] * inv - mu * mu;
        const float rs  = rsqrtf(var + 1e-5f);
        const float sc  = g1[t] * rs;
        sSc1[t] = sc;
        sSh1[t] = b1[t] - mu * sc;
    }
    __syncthreads();

    const int rtile = blockIdx.x, half = blockIdx.y;
    const int r0 = rtile * 64;
    const int dsub = half * 256 + w * 64;
    const int qd = lane >> 4, s = lane & 15;
    const int mc0 = qd * 8;

    bf16x8 bfr[4][2];
#pragma unroll
    for (int f = 0; f < 4; ++f)
#pragma unroll
        for (int g = 0; g < 2; ++g)
            bfr[f][g] = *(const bf16x8*)&W2b[(size_t)(dsub + f * 16 + s) * 64 + mc0 + g * 32];

    f32x4 acc[4][4];
#pragma unroll
    for (int rt = 0; rt < 4; ++rt)
#pragma unroll
        for (int f = 0; f < 4; ++f) acc[rt][f] = (f32x4){0.f,0.f,0.f,0.f};

#pragma unroll
    for (int rt = 0; rt < 4; ++rt) {
        const int row = r0 + rt * 16 + s;
#pragma unroll
        for (int g = 0; g < 2; ++g) {
            const int mc = mc0 + g * 32;
            const uint4 u0 = *(const uint4*)&HMM[(size_t)row * 64 + mc];
            const uint4 u1 = *(const uint4*)&HMM[(size_t)row * 64 + mc + 4];
            float v[8];
#pragma unroll
            for (int i = 0; i < 4; ++i) {
                const uint ua = ((const uint*)&u0)[i];
                const uint ub = ((const uint*)&u1)[i];
                const float c0 = sSc1[mc + i],     h0 = sSh1[mc + i];
                const float c4 = sSc1[mc + 4 + i], h4 = sSh1[mc + 4 + i];
                const float a0 = c0 >= 0.f ? bits2f(ua << 16) : bits2f(ua & 0xffff0000u);
                const float a4 = c4 >= 0.f ? bits2f(ub << 16) : bits2f(ub & 0xffff0000u);
                v[i]     = lrelu(a0 * c0 + h0);
                v[i + 4] = lrelu(a4 * c4 + h4);
            }
            uint4 pk;
            pk.x = f2b(v[0]) | (f2b(v[1]) << 16);
            pk.y = f2b(v[2]) | (f2b(v[3]) << 16);
            pk.z = f2b(v[4]) | (f2b(v[5]) << 16);
            pk.w = f2b(v[6]) | (f2b(v[7]) << 16);
            if (half == 0) *(uint4*)&Hb[(size_t)row * 64 + mc] = pk;
            union { uint4 u; bf16x8 b; } cv; cv.u = pk;
#pragma unroll
            for (int f = 0; f < 4; ++f)
                acc[rt][f] = __builtin_amdgcn_mfma_f32_16x16x32_bf16(cv.b, bfr[f][g], acc[rt][f], 0, 0, 0);
        }
    }

#pragma unroll
    for (int f = 0; f < 4; ++f) {
        float ss = 0.f, qq = 0.f;
#pragma unroll
        for (int rt = 0; rt < 4; ++rt)
#pragma unroll
            for (int i = 0; i < 4; ++i) {
                const float vv = acc[rt][f][i];
                ss += vv; qq += vv * vv;
            }
        ss += __shfl_xor(ss, 16); ss += __shfl_xor(ss, 32);
        qq += __shfl_xor(qq, 16); qq += __shfl_xor(qq, 32);
        if (lane < 16) {
            const int d = dsub + f * 16 + s;
            atomicAdd(&P2a[d], ss);
            atomicAdd(&P2a[512 + d], qq);
        }
    }
}

/* ------------------------------------------------------------------ */
/* out: finalize BN2, h2 recompute MFMA, BN2+leaky, write. */
__global__ __launch_bounds__(256) void k_out(const ushort* __restrict__ Hb,
                                             const ushort* __restrict__ W2b,
                                             const float* __restrict__ P2a,
                                             const float* __restrict__ g2,
                                             const float* __restrict__ b2,
                                             float* __restrict__ out) {
    __shared__ float sSc2[256], sSh2[256];
    const int t = threadIdx.x, lane = t & 63, w = t >> 6;
    const int rtile = blockIdx.x, half = blockIdx.y;
    {
        const int d = half * 256 + t;
        const float inv = 1.f / (float)R_;
        const float mu  = P2a[d] * inv;
        const float var = P2a[512 + d] * inv - mu * mu;
        const float rs  = rsqrtf(var + 1e-5f);
        const float sc  = g2[d] * rs;
        sSc2[t] = sc;
        sSh2[t] = b2[d] - mu * sc;
    }
    __syncthreads();

    const int r0 = rtile * 64;
    const int dsub = half * 256 + w * 64;
    const int qd = lane >> 4, s = lane & 15;
    const int mc0 = qd * 8;

    bf16x8 bfr[4][2];
#pragma unroll
    for (int f = 0; f < 4; ++f)
#pragma unroll
        for (int g = 0; g < 2; ++g)
            bfr[f][g] = *(const bf16x8*)&W2b[(size_t)(dsub + f * 16 + s) * 64 + mc0 + g * 32];

    f32x4 acc[4][4];
#pragma unroll
    for (int rt = 0; rt < 4; ++rt)
#pragma unroll
        for (int f = 0; f < 4; ++f) acc[rt][f] = (f32x4){0.f,0.f,0.f,0.f};

#pragma unroll
    for (int rt = 0; rt < 4; ++rt) {
        const int row = r0 + rt * 16 + s;
#pragma unroll
        for (int g = 0; g < 2; ++g) {
            const bf16x8 af = *(const bf16x8*)&Hb[(size_t)row * 64 + mc0 + g * 32];
#pragma unroll
            for (int f = 0; f < 4; ++f)
                acc[rt][f] = __builtin_amdgcn_mfma_f32_16x16x32_bf16(af, bfr[f][g], acc[rt][f], 0, 0, 0);
        }
    }

#pragma unroll
    for (int rt = 0; rt < 4; ++rt)
#pragma unroll
        for (int f = 0; f < 4; ++f) {
            const int dl = w * 64 + f * 16 + s;
            const float c2 = sSc2[dl], h2 = sSh2[dl];
            const int d = dsub + f * 16 + s;
#pragma unroll
            for (int i = 0; i < 4; ++i) {
                const float vv = lrelu(acc[rt][f][i] * c2 + h2);
                out[(size_t)(r0 + rt * 16 + qd * 4 + i) * 512 + d] = vv;
            }
        }
}

/* ------------------------------------------------------------------ */
extern "C" void kernel_launch(void* const* d_in, const int* in_sizes, int n_in,
                              void* d_out, int out_size, void* d_ws, size_t ws_size,
                              hipStream_t stream) {
    const float* x   = (const float*)d_in[0];
    const int*   idx = (const int*)d_in[1];
    const float* W1  = (const float*)d_in[2];
    const float* g1  = (const float*)d_in[3];
    const float* b1  = (const float*)d_in[4];
    const float* W2  = (const float*)d_in[5];
    const float* g2  = (const float*)d_in[6];
    const float* b2  = (const float*)d_in[7];
    float* out = (float*)d_out;
    float* ws  = (float*)d_ws;

    ushort* Y    = (ushort*)(ws + WS_Y);
    uint*   HMM  = (uint*)(ws + WS_HMM);
    float*  P1a  = ws + WS_P1A;
    float*  P2a  = ws + WS_P2A;
    ushort* Hb   = (ushort*)(ws + WS_HB);
    ushort* W1b  = (ushort*)(ws + WS_W1B);
    ushort* W2b  = (ushort*)(ws + WS_W2B);

    k_prep  <<<dim3(56),      dim3(256), 0, stream>>>(W1, W2, W1b, W2b, P1a, P2a);
    k_yz    <<<dim3(R_ / 32), dim3(256), 0, stream>>>(x, W1b, Y);
    k_gather<<<dim3(R_ / 16), dim3(256), 0, stream>>>(Y, idx, HMM, P1a);
    k_qsum  <<<dim3(128, 2),  dim3(256), 0, stream>>>(HMM, P1a, g1, b1, W2b, Hb, P2a);
    k_out   <<<dim3(128, 2),  dim3(256), 0, stream>>>(Hb, W2b, P2a, g2, b2, out);
}